// Round 10
// baseline (365.022 us; speedup 1.0000x reference)
//
#include <hip/hip_runtime.h>
#include <hip/hip_bf16.h>
#include <math.h>

#define T_TOK 32768
#define D_DIM 512
#define E_EXP 16
#define F_DIM 1024
#define C_CAP 2048

typedef __attribute__((ext_vector_type(8))) __bf16 bf16x8;
typedef __attribute__((ext_vector_type(4))) float f32x4;

__device__ __forceinline__ unsigned short f2bf(float f) {
  unsigned u = __float_as_uint(f);
  u += 0x7FFFu + ((u >> 16) & 1u);   // round-to-nearest-even
  return (unsigned short)(u >> 16);
}

__device__ __forceinline__ void gld16(const void* gptr, void* ldsptr) {
  __builtin_amdgcn_global_load_lds(
      (__attribute__((address_space(1))) void*)(void*)gptr,
      (__attribute__((address_space(3))) void*)ldsptr, 16, 0, 0);
}

// merged transposed-convert for w1 and w2: [E][R][Cc] fp32 -> [E][Cc][R] bf16
// grid.x: [0,1024) -> w1 (R=512, Cc=2048); [1024,1536) -> w2 (R=1024, Cc=512)
__global__ void transpose_conv2_kernel(const float* __restrict__ w1,
                                       const float* __restrict__ w2,
                                       unsigned short* __restrict__ w1t,
                                       unsigned short* __restrict__ w2t) {
  __shared__ float tile[32][33];
  int e = blockIdx.y;
  int b = blockIdx.x;
  const float* in; unsigned short* out; int R, Cc, bx, by;
  if (b < 1024) { in = w1; out = w1t; R = D_DIM; Cc = 2 * F_DIM; bx = b & 63; by = b >> 6; }
  else { b -= 1024; in = w2; out = w2t; R = F_DIM; Cc = D_DIM; bx = b & 15; by = b >> 4; }
  int r0 = by * 32, c0 = bx * 32;
  const float* pin = in + (size_t)e * R * Cc;
  unsigned short* pout = out + (size_t)e * R * Cc;
  int tx = threadIdx.x, ty = threadIdx.y;  // 32 x 8
  #pragma unroll
  for (int i = 0; i < 32; i += 8)
    tile[ty + i][tx] = pin[(size_t)(r0 + ty + i) * Cc + c0 + tx];
  __syncthreads();
  int t = ty * 32 + tx;
  int oc = t >> 3, og = t & 7;
  ushort4 o;
  o.x = f2bf(tile[og * 4 + 0][oc]);
  o.y = f2bf(tile[og * 4 + 1][oc]);
  o.z = f2bf(tile[og * 4 + 2][oc]);
  o.w = f2bf(tile[og * 4 + 3][oc]);
  *(ushort4*)&pout[(size_t)(c0 + oc) * R + r0 + og * 4] = o;
}

// ---------------- gating (+ fused x -> bf16 conversion) ----------------
// writes ALL 16 w_et entries per token (0 for non-top2) -> no w_et memset needed
__global__ __launch_bounds__(256) void gate_kernel(
    const float* __restrict__ x, const float* __restrict__ wg,
    float* __restrict__ w_et, float* __restrict__ phi_sum,
    unsigned short* __restrict__ xb) {
  __shared__ float wgl[D_DIM * E_EXP];
  __shared__ float phil[E_EXP];
  int tid = threadIdx.x;
  for (int i = tid; i < D_DIM * E_EXP; i += 256) wgl[i] = wg[i];
  if (tid < E_EXP) phil[tid] = 0.f;
  __syncthreads();

  int g = tid >> 4;
  int e = tid & 15;
  int t = blockIdx.x * 16 + g;

  float acc = 0.f;
  const float* xr = x + (size_t)t * D_DIM;
  #pragma unroll 4
  for (int d = 0; d < D_DIM; d += 4) {
    float4 xv = *(const float4*)(xr + d);
    acc = fmaf(xv.x, wgl[(d + 0) * 16 + e], acc);
    acc = fmaf(xv.y, wgl[(d + 1) * 16 + e], acc);
    acc = fmaf(xv.z, wgl[(d + 2) * 16 + e], acc);
    acc = fmaf(xv.w, wgl[(d + 3) * 16 + e], acc);
  }

  unsigned short* xrow = xb + (size_t)t * D_DIM;
  #pragma unroll
  for (int j = 0; j < 8; ++j) {
    int idx = j * 16 + e;
    float4 v = *(const float4*)(xr + idx * 4);
    ushort4 o;
    o.x = f2bf(v.x); o.y = f2bf(v.y); o.z = f2bf(v.z); o.w = f2bf(v.w);
    ((ushort4*)xrow)[idx] = o;
  }

  float m = acc;
  for (int off = 8; off; off >>= 1) m = fmaxf(m, __shfl_xor(m, off));
  float p = expf(acc - m);
  float s = p;
  for (int off = 8; off; off >>= 1) s += __shfl_xor(s, off);
  float score = p / s;
  atomicAdd(&phil[e], score);

  float v1 = score; int i1 = e;
  for (int off = 8; off; off >>= 1) {
    float ov = __shfl_xor(v1, off); int oi = __shfl_xor(i1, off);
    if (ov > v1 || (ov == v1 && oi < i1)) { v1 = ov; i1 = oi; }
  }
  float sc2 = (e == i1) ? -1.f : score;
  float v2 = sc2; int i2 = e;
  for (int off = 8; off; off >>= 1) {
    float ov = __shfl_xor(v2, off); int oi = __shfl_xor(i2, off);
    if (ov > v2 || (ov == v2 && oi < i2)) { v2 = ov; i2 = oi; }
  }
  float val = (e == i1) ? v1 : ((e == i2) ? v2 : 0.f);
  w_et[(size_t)e * T_TOK + t] = val;
  __syncthreads();
  if (tid < E_EXP) atomicAdd(&phi_sum[tid], phil[tid]);
}

__global__ void aux_kernel(const float* __restrict__ phi_sum, float* __restrict__ out_aux) {
  if (threadIdx.x == 0) {
    float s = 0.f;
    for (int e = 0; e < E_EXP; ++e) {
      float pm = phi_sum[e] / (float)T_TOK;
      s += pm * pm;
    }
    *out_aux = (float)E_EXP * s;
  }
}

// ===== top-C selection: 3-level radix (11/11/10); pick fused via last-block =====
template<int P>
__global__ __launch_bounds__(256) void s_hist(
    const float* __restrict__ w_et, unsigned* __restrict__ hist,
    unsigned* __restrict__ prefix, unsigned* __restrict__ krem,
    unsigned* __restrict__ done, unsigned* __restrict__ arrive) {
  int c = blockIdx.x, e = blockIdx.y, tid = threadIdx.x;
  if (P > 0 && done[e]) return;
  __shared__ unsigned lh[2048];
  for (int i = tid; i < 2048; i += 256) lh[i] = 0;
  __syncthreads();
  const float* w = w_et + (size_t)e * T_TOK + c * 2048;
  unsigned pfx = (P > 0) ? prefix[e] : 0u;
  #pragma unroll
  for (int i = 0; i < 8; ++i) {
    unsigned b = __float_as_uint(w[i * 256 + tid]);
    if (P == 0) { if (b) atomicAdd(&lh[b >> 21], 1u); }
    else if (P == 1) { if ((b >> 21) == (pfx >> 21)) atomicAdd(&lh[(b >> 10) & 0x7FFu], 1u); }
    else { if ((b >> 10) == (pfx >> 10)) atomicAdd(&lh[b & 0x3FFu], 1u); }
  }
  __syncthreads();
  for (int i = tid; i < 2048; i += 256)
    if (lh[i]) atomicAdd(&hist[e * 2048 + i], lh[i]);

  __threadfence();
  __shared__ unsigned s_last;
  if (tid == 0) s_last = (atomicAdd(&arrive[P * 16 + e], 1u) == 15u) ? 1u : 0u;
  __syncthreads();
  if (!s_last) return;
  __threadfence();
  if (tid >= 64) return;
  int lane = tid;
  const int BPL = (P == 2) ? 16 : 32;
  const int SH = (P == 0) ? 21 : (P == 1) ? 10 : 0;
  const unsigned* h = hist + e * 2048;
  unsigned S = 0;
  for (int i = 0; i < BPL; ++i) S += h[lane * BPL + i];
  unsigned U = S;
  #pragma unroll
  for (int off = 1; off < 64; off <<= 1) {
    unsigned t2 = __shfl_down(U, off);
    if (lane + off < 64) U += t2;
  }
  unsigned Unext = __shfl_down(U, 1);
  if (lane == 63) Unext = 0;
  unsigned k = (P == 0) ? (unsigned)C_CAP : krem[e];
  if (P == 0 && lane == 0) {
    if (U < k) { done[e] = 1; prefix[e] = 0; krem[e] = 0; }
    else done[e] = 0;
  }
  if (U >= k && Unext < k) {
    unsigned cum = Unext; int chosen = 0; unsigned knew = 0;
    for (int i = BPL - 1; i >= 0; --i) {
      unsigned hh = h[lane * BPL + i];
      if (cum + hh >= k) { chosen = lane * BPL + i; knew = k - cum; break; }
      cum += hh;
    }
    if (P == 0) prefix[e] = ((unsigned)chosen) << SH;
    else prefix[e] = prefix[e] | (((unsigned)chosen) << SH);
    krem[e] = knew;
  }
}

__global__ __launch_bounds__(256) void s_count(
    const float* __restrict__ w_et, const unsigned* __restrict__ prefix,
    unsigned* __restrict__ cnt) {
  int c = blockIdx.x, e = blockIdx.y, tid = threadIdx.x;
  unsigned thr = prefix[e];
  const uint4* up = (const uint4*)(w_et + (size_t)e * T_TOK + c * 2048 + tid * 8);
  uint4 va = up[0], vb = up[1];
  unsigned gt = 0, eq = 0;
  unsigned vals[8] = {va.x, va.y, va.z, va.w, vb.x, vb.y, vb.z, vb.w};
  #pragma unroll
  for (int i = 0; i < 8; ++i) {
    if (vals[i] > thr) gt++;
    else if (vals[i] == thr) eq++;
  }
  __shared__ unsigned sc[256];
  sc[tid] = (gt << 16) | eq;
  __syncthreads();
  for (int s = 128; s; s >>= 1) {
    if (tid < s) sc[tid] += sc[tid + s];
    __syncthreads();
  }
  if (tid == 0) cnt[e * 16 + c] = sc[0];
}

// s_write: compaction (exact tie-break: gt unordered, eq ascending token index)
__global__ __launch_bounds__(256) void s_write(
    const float* __restrict__ w_et, const unsigned* __restrict__ prefix,
    const unsigned* __restrict__ cnt,
    int* __restrict__ sel_idx, float* __restrict__ sel_w) {
  int c = blockIdx.x, e = blockIdx.y, tid = threadIdx.x;
  unsigned thr = prefix[e];
  __shared__ unsigned s_gb, s_eb, s_gt, s_eq;
  if (tid == 0) {
    unsigned g = 0, q = 0, gb = 0, eb = 0;
    #pragma unroll
    for (int c2 = 0; c2 < 16; ++c2) {
      unsigned p = cnt[e * 16 + c2];
      if (c2 < c) { gb += p >> 16; eb += p & 0xFFFFu; }
      g += p >> 16; q += p & 0xFFFFu;
    }
    s_gb = gb; s_eb = eb; s_gt = g; s_eq = (unsigned)C_CAP - g;
  }
  const uint4* up = (const uint4*)(w_et + (size_t)e * T_TOK + c * 2048 + tid * 8);
  uint4 va = up[0], vb = up[1];
  unsigned vals[8] = {va.x, va.y, va.z, va.w, vb.x, vb.y, vb.z, vb.w};
  unsigned gt = 0, eq = 0;
  #pragma unroll
  for (int i = 0; i < 8; ++i) {
    if (vals[i] > thr) gt++;
    else if (vals[i] == thr) eq++;
  }
  __shared__ unsigned sc[256];
  unsigned mine = (gt << 16) | eq;
  sc[tid] = mine;
  __syncthreads();
  for (int off = 1; off < 256; off <<= 1) {
    unsigned add = (tid >= off) ? sc[tid - off] : 0u;
    __syncthreads();
    sc[tid] += add;
    __syncthreads();
  }
  unsigned excl = sc[tid] - mine;
  unsigned gpos = s_gb + (excl >> 16);
  unsigned qpos = s_eb + (excl & 0xFFFFu);
  unsigned gtotal = s_gt, eqtake = s_eq;
  int* si = sel_idx + (size_t)e * C_CAP;
  float* sw = sel_w + (size_t)e * C_CAP;
  int tokbase = c * 2048 + tid * 8;
  #pragma unroll
  for (int i = 0; i < 8; ++i) {
    unsigned b = vals[i];
    if (b > thr) {
      si[gpos] = tokbase + i; sw[gpos] = __uint_as_float(b); gpos++;
    } else if (b == thr && qpos < eqtake) {
      si[gtotal + qpos] = tokbase + i; sw[gtotal + qpos] = __uint_as_float(b); qpos++;
    }
  }
}

// ===== GEMMs: 128x128 tile, BK=32, 3-buffer 2-deep pipeline, counted vmcnt(4) =====
// (R4-proven structure.) LDS chunk swizzle (64B rows = 4x16B chunks):
// lds_chunk = k_chunk ^ ((row>>1)&3); gld16 dest linear, source pre-swizzled.

#define PIPE_BARRIER() do { __builtin_amdgcn_s_barrier(); __builtin_amdgcn_sched_barrier(0); } while (0)

// ---- GEMM1: h = gather(x) @ w1[e], SwiGLU fused -> act bf16 ----
// grid e(16) x mt(16) x nt(16); tile 128 tok x (64 h1 + 64 h2); waves 2M x 2N
__global__ __launch_bounds__(256, 3) void gemm1_kernel(
    const unsigned short* __restrict__ xb,    // [T][D] bf16
    const unsigned short* __restrict__ w1t,   // [E][2F][D] bf16
    const int* __restrict__ sel_idx,          // [E][C]
    unsigned short* __restrict__ act) {       // [E][C][F] bf16
  __shared__ __align__(16) unsigned short As[3 * 4096];
  __shared__ __align__(16) unsigned short Bs[3 * 4096];
  int bid = (blockIdx.x & 7) * 512 + (blockIdx.x >> 3);
  int nt = bid & 15, mt = (bid >> 4) & 15, e = bid >> 8;
  int tid = threadIdx.x, lane = tid & 63, wid = tid >> 6;
  int wr = wid >> 1, wc = wid & 1;
  int cl = lane & 15, rg = lane >> 4;

  int c0 = tid, c1 = 256 + tid;
  int r0 = c0 >> 2, gk0 = (c0 & 3) ^ ((r0 >> 1) & 3);
  int r1 = c1 >> 2, gk1 = (c1 & 3) ^ ((r1 >> 1) & 3);
  int tok0 = sel_idx[e * C_CAP + mt * 128 + r0];
  int tok1 = sel_idx[e * C_CAP + mt * 128 + r1];
  const unsigned short* ag0 = xb + (size_t)tok0 * D_DIM + gk0 * 8;
  const unsigned short* ag1 = xb + (size_t)tok1 * D_DIM + gk1 * 8;
  int hcol0 = (r0 < 64) ? (nt * 64 + r0) : (F_DIM + nt * 64 + (r0 - 64));
  int hcol1 = (r1 < 64) ? (nt * 64 + r1) : (F_DIM + nt * 64 + (r1 - 64));
  const unsigned short* bg0 = w1t + ((size_t)e * 2 * F_DIM + hcol0) * D_DIM + gk0 * 8;
  const unsigned short* bg1 = w1t + ((size_t)e * 2 * F_DIM + hcol1) * D_DIM + gk1 * 8;
  char* Ab = (char*)As;
  char* Bb = (char*)Bs;

#define G1_STAGE(buf, kt) do { \
    gld16(ag0 + (kt) * 32, Ab + (buf) * 8192 + tid * 16); \
    gld16(ag1 + (kt) * 32, Ab + (buf) * 8192 + 4096 + tid * 16); \
    gld16(bg0 + (kt) * 32, Bb + (buf) * 8192 + tid * 16); \
    gld16(bg1 + (kt) * 32, Bb + (buf) * 8192 + 4096 + tid * 16); \
  } while (0)

  f32x4 zero = {0.f, 0.f, 0.f, 0.f};
  f32x4 acc[4][4];
  #pragma unroll
  for (int m = 0; m < 4; ++m)
    #pragma unroll
    for (int n = 0; n < 4; ++n) acc[m][n] = zero;

#define G1_COMPUTE(buf) do { \
    const unsigned short* Ap = As + (buf) * 4096; \
    const unsigned short* Bp = Bs + (buf) * 4096; \
    bf16x8 av[4], bv[4]; \
    _Pragma("unroll") \
    for (int m = 0; m < 4; ++m) { \
      int ra = wr * 64 + m * 16 + cl; \
      av[m] = *(const bf16x8*)&Ap[(ra * 4 + (rg ^ ((ra >> 1) & 3))) * 8]; \
    } \
    _Pragma("unroll") \
    for (int n = 0; n < 4; ++n) { \
      int rb = ((n < 2) ? (wc * 32 + n * 16) : (64 + wc * 32 + (n - 2) * 16)) + cl; \
      bv[n] = *(const bf16x8*)&Bp[(rb * 4 + (rg ^ ((rb >> 1) & 3))) * 8]; \
    } \
    _Pragma("unroll") \
    for (int m = 0; m < 4; ++m) \
      _Pragma("unroll") \
      for (int n = 0; n < 4; ++n) \
        acc[m][n] = __builtin_amdgcn_mfma_f32_16x16x32_bf16(av[m], bv[n], acc[m][n], 0, 0, 0); \
  } while (0)

  const int NK = D_DIM / 32;  // 16
  G1_STAGE(0, 0);
  G1_STAGE(1, 1);
  int bc = 0, bs = 2;
  for (int kt = 0; kt < NK - 1; ++kt) {
    asm volatile("s_waitcnt vmcnt(4)" ::: "memory");
    PIPE_BARRIER();
    if (kt + 2 < NK) { G1_STAGE(bs, kt + 2); bs = (bs == 2) ? 0 : bs + 1; }
    __builtin_amdgcn_sched_barrier(0);
    G1_COMPUTE(bc);
    bc = (bc == 2) ? 0 : bc + 1;
  }
  asm volatile("s_waitcnt vmcnt(0)" ::: "memory");
  PIPE_BARRIER();
  G1_COMPUTE(bc);

  // SwiGLU epilogue: n in {0,1} = h1 frags, n+2 = matching h2 frags
  #pragma unroll
  for (int m = 0; m < 4; ++m) {
    #pragma unroll
    for (int n = 0; n < 2; ++n) {
      #pragma unroll
      for (int r = 0; r < 4; ++r) {
        int row = mt * 128 + wr * 64 + m * 16 + rg * 4 + r;
        int col = nt * 64 + wc * 32 + n * 16 + cl;
        float h1 = acc[m][n][r];
        float h2 = acc[m][n + 2][r];
        float sg = h2 / (1.f + __expf(-h2));
        act[((size_t)e * C_CAP + row) * F_DIM + col] = f2bf(h1 * sg);
      }
    }
  }
#undef G1_STAGE
#undef G1_COMPUTE
}

// ---- GEMM2: out += (act @ w2[e]) * sel_w, atomic scatter (<=2 adds/token) ----
// grid e(16) x mt(16) x nt(4); tile 128 x 128; waves 2M x 2N
__global__ __launch_bounds__(256, 3) void gemm2_kernel(
    const unsigned short* __restrict__ act,   // [E][C][F] bf16
    const unsigned short* __restrict__ w2t,   // [E][D][F] bf16
    const int* __restrict__ sel_idx,
    const float* __restrict__ sel_w,
    float* __restrict__ out) {                // [T][D] fp32
  __shared__ __align__(16) unsigned short As[3 * 4096];
  __shared__ __align__(16) unsigned short Bs[3 * 4096];
  int bid = (blockIdx.x & 7) * 128 + (blockIdx.x >> 3);
  int nt = bid & 3, mt = (bid >> 2) & 15, e = bid >> 6;
  int tid = threadIdx.x, lane = tid & 63, wid = tid >> 6;
  int wr = wid >> 1, wc = wid & 1;
  int cl = lane & 15, rg = lane >> 4;

  int c0 = tid, c1 = 256 + tid;
  int r0 = c0 >> 2, gk0 = (c0 & 3) ^ ((r0 >> 1) & 3);
  int r1 = c1 >> 2, gk1 = (c1 & 3) ^ ((r1 >> 1) & 3);
  const unsigned short* ag0 = act + ((size_t)e * C_CAP + mt * 128 + r0) * F_DIM + gk0 * 8;
  const unsigned short* ag1 = act + ((size_t)e * C_CAP + mt * 128 + r1) * F_DIM + gk1 * 8;
  const unsigned short* bg0 = w2t + ((size_t)e * D_DIM + nt * 128 + r0) * F_DIM + gk0 * 8;
  const unsigned short* bg1 = w2t + ((size_t)e * D_DIM + nt * 128 + r1) * F_DIM + gk1 * 8;
  char* Ab = (char*)As;
  char* Bb = (char*)Bs;

#define G2_STAGE(buf, kt) do { \
    gld16(ag0 + (kt) * 32, Ab + (buf) * 8192 + tid * 16); \
    gld16(ag1 + (kt) * 32, Ab + (buf) * 8192 + 4096 + tid * 16); \
    gld16(bg0 + (kt) * 32, Bb + (buf) * 8192 + tid * 16); \
    gld16(bg1 + (kt) * 32, Bb + (buf) * 8192 + 4096 + tid * 16); \
  } while (0)

  f32x4 zero = {0.f, 0.f, 0.f, 0.f};
  f32x4 acc[4][4];
  #pragma unroll
  for (int m = 0; m < 4; ++m)
    #pragma unroll
    for (int n = 0; n < 4; ++n) acc[m][n] = zero;

#define G2_COMPUTE(buf) do { \
    const unsigned short* Ap = As + (buf) * 4096; \
    const unsigned short* Bp = Bs + (buf) * 4096; \
    bf16x8 av[4], bv[4]; \
    _Pragma("unroll") \
    for (int m = 0; m < 4; ++m) { \
      int ra = wr * 64 + m * 16 + cl; \
      av[m] = *(const bf16x8*)&Ap[(ra * 4 + (rg ^ ((ra >> 1) & 3))) * 8]; \
    } \
    _Pragma("unroll") \
    for (int n = 0; n < 4; ++n) { \
      int rb = wc * 64 + n * 16 + cl; \
      bv[n] = *(const bf16x8*)&Bp[(rb * 4 + (rg ^ ((rb >> 1) & 3))) * 8]; \
    } \
    _Pragma("unroll") \
    for (int m = 0; m < 4; ++m) \
      _Pragma("unroll") \
      for (int n = 0; n < 4; ++n) \
        acc[m][n] = __builtin_amdgcn_mfma_f32_16x16x32_bf16(av[m], bv[n], acc[m][n], 0, 0, 0); \
  } while (0)

  const int NK = F_DIM / 32;  // 32
  G2_STAGE(0, 0);
  G2_STAGE(1, 1);
  int bc = 0, bs = 2;
  for (int kt = 0; kt < NK - 1; ++kt) {
    asm volatile("s_waitcnt vmcnt(4)" ::: "memory");
    PIPE_BARRIER();
    if (kt + 2 < NK) { G2_STAGE(bs, kt + 2); bs = (bs == 2) ? 0 : bs + 1; }
    __builtin_amdgcn_sched_barrier(0);
    G2_COMPUTE(bc);
    bc = (bc == 2) ? 0 : bc + 1;
  }
  asm volatile("s_waitcnt vmcnt(0)" ::: "memory");
  PIPE_BARRIER();
  G2_COMPUTE(bc);

  #pragma unroll
  for (int m = 0; m < 4; ++m) {
    #pragma unroll
    for (int r = 0; r < 4; ++r) {
      int slot = mt * 128 + wr * 64 + m * 16 + rg * 4 + r;
      float wgt = sel_w[e * C_CAP + slot];
      int tok = sel_idx[e * C_CAP + slot];
      float* orow = out + (size_t)tok * D_DIM;
      #pragma unroll
      for (int n = 0; n < 4; ++n) {
        int col = nt * 128 + wc * 64 + n * 16 + cl;
        atomicAdd(&orow[col], acc[m][n][r] * wgt);
      }
    }
  }
#undef G2_STAGE
#undef G2_COMPUTE
}

// ---------------- launch ----------------
extern "C" void kernel_launch(void* const* d_in, const int* in_sizes, int n_in,
                              void* d_out, int out_size, void* d_ws, size_t ws_size,
                              hipStream_t stream) {
  const float* x  = (const float*)d_in[0];
  const float* wg = (const float*)d_in[1];
  const float* w1 = (const float*)d_in[2];
  const float* w2 = (const float*)d_in[3];
  float* out = (float*)d_out;

  char* ws = (char*)d_ws;
  size_t off = 0;
  auto carve = [&](size_t bytes) -> void* {
    void* p = ws + off;
    off += (bytes + 255) & ~(size_t)255;
    return p;
  };
  float* w_et            = (float*)carve((size_t)E_EXP * T_TOK * 4);
  int* sel_i             = (int*)carve((size_t)E_EXP * C_CAP * 4);
  float* sel_wv          = (float*)carve((size_t)E_EXP * C_CAP * 4);
  unsigned short* xb     = (unsigned short*)carve((size_t)T_TOK * D_DIM * 2);
  unsigned short* w1t    = (unsigned short*)carve((size_t)E_EXP * 2 * F_DIM * D_DIM * 2);
  unsigned short* w2t    = (unsigned short*)carve((size_t)E_EXP * D_DIM * F_DIM * 2);
  unsigned short* actb   = (unsigned short*)carve((size_t)E_EXP * C_CAP * F_DIM * 2);
  // contiguous zero-region: phi .. arrive (all sizes multiples of 256 B)
  float* phi             = (float*)carve(256);
  unsigned* hist0        = (unsigned*)carve((size_t)E_EXP * 2048 * 4);
  unsigned* hist1        = (unsigned*)carve((size_t)E_EXP * 2048 * 4);
  unsigned* hist2        = (unsigned*)carve((size_t)E_EXP * 2048 * 4);
  unsigned* prefix       = (unsigned*)carve(256);
  unsigned* krem         = (unsigned*)carve(256);
  unsigned* done         = (unsigned*)carve(256);
  unsigned* cnt          = (unsigned*)carve(1024);
  unsigned* arrive       = (unsigned*)carve(256);
  size_t zero_bytes = (size_t)((char*)(arrive + 64) - (char*)phi);
  if (off > ws_size) return;

  hipMemsetAsync(phi, 0, zero_bytes, stream);               // phi+hists+ctrl in one shot
  hipMemsetAsync(d_out, 0, (size_t)out_size * 4, stream);   // atomic target must be 0

  transpose_conv2_kernel<<<dim3(1536, 16), dim3(32, 8), 0, stream>>>(w1, w2, w1t, w2t);
  gate_kernel<<<T_TOK / 16, 256, 0, stream>>>(x, wg, w_et, phi, xb);

  s_hist<0><<<dim3(16, 16), 256, 0, stream>>>(w_et, hist0, prefix, krem, done, arrive);
  s_hist<1><<<dim3(16, 16), 256, 0, stream>>>(w_et, hist1, prefix, krem, done, arrive);
  s_hist<2><<<dim3(16, 16), 256, 0, stream>>>(w_et, hist2, prefix, krem, done, arrive);
  s_count<<<dim3(16, 16), 256, 0, stream>>>(w_et, prefix, cnt);
  s_write<<<dim3(16, 16), 256, 0, stream>>>(w_et, prefix, cnt, sel_i, sel_wv);

  aux_kernel<<<1, 64, 0, stream>>>(phi, out + (size_t)T_TOK * D_DIM);
  gemm1_kernel<<<E_EXP * 16 * 16, 256, 0, stream>>>(xb, w1t, sel_i, actb);
  gemm2_kernel<<<E_EXP * 16 * 4, 256, 0, stream>>>(actb, w2t, sel_i, sel_wv, out);
}

// Round 11
// 333.865 us; speedup vs baseline: 1.0933x; 1.0933x over previous
//
#include <hip/hip_runtime.h>
#include <hip/hip_bf16.h>
#include <math.h>

#define T_TOK 32768
#define D_DIM 512
#define E_EXP 16
#define F_DIM 1024
#define C_CAP 2048

typedef __attribute__((ext_vector_type(8))) __bf16 bf16x8;
typedef __attribute__((ext_vector_type(4))) float f32x4;

__device__ __forceinline__ unsigned short f2bf(float f) {
  unsigned u = __float_as_uint(f);
  u += 0x7FFFu + ((u >> 16) & 1u);   // round-to-nearest-even
  return (unsigned short)(u >> 16);
}

__device__ __forceinline__ void gld16(const void* gptr, void* ldsptr) {
  __builtin_amdgcn_global_load_lds(
      (__attribute__((address_space(1))) void*)(void*)gptr,
      (__attribute__((address_space(3))) void*)ldsptr, 16, 0, 0);
}

// in: [E][R][Cc] fp32 -> out: [E][Cc][R] bf16 (transposed convert)
__global__ void transpose_conv_kernel(const float* __restrict__ in,
                                      unsigned short* __restrict__ out,
                                      int R, int Cc) {
  __shared__ float tile[32][33];
  int e = blockIdx.z;
  int r0 = blockIdx.y * 32, c0 = blockIdx.x * 32;
  const float* pin = in + (size_t)e * R * Cc;
  unsigned short* pout = out + (size_t)e * R * Cc;
  int tx = threadIdx.x, ty = threadIdx.y;  // 32 x 8
  #pragma unroll
  for (int i = 0; i < 32; i += 8)
    tile[ty + i][tx] = pin[(size_t)(r0 + ty + i) * Cc + c0 + tx];
  __syncthreads();
  #pragma unroll
  for (int i = 0; i < 32; i += 8)
    pout[(size_t)(c0 + ty + i) * R + r0 + tx] = f2bf(tile[tx][ty + i]);
}

// ---------------- gating (+ fused x -> bf16 conversion) ----------------
__global__ __launch_bounds__(256) void gate_kernel(
    const float* __restrict__ x, const float* __restrict__ wg,
    float* __restrict__ w_et, float* __restrict__ phi_sum,
    unsigned short* __restrict__ xb) {
  __shared__ float wgl[D_DIM * E_EXP];
  __shared__ float phil[E_EXP];
  int tid = threadIdx.x;
  for (int i = tid; i < D_DIM * E_EXP; i += 256) wgl[i] = wg[i];
  if (tid < E_EXP) phil[tid] = 0.f;
  __syncthreads();

  int g = tid >> 4;
  int e = tid & 15;
  int t = blockIdx.x * 16 + g;

  float acc = 0.f;
  const float* xr = x + (size_t)t * D_DIM;
  #pragma unroll 4
  for (int d = 0; d < D_DIM; d += 4) {
    float4 xv = *(const float4*)(xr + d);
    acc = fmaf(xv.x, wgl[(d + 0) * 16 + e], acc);
    acc = fmaf(xv.y, wgl[(d + 1) * 16 + e], acc);
    acc = fmaf(xv.z, wgl[(d + 2) * 16 + e], acc);
    acc = fmaf(xv.w, wgl[(d + 3) * 16 + e], acc);
  }

  // fused conversion: group lanes cover the row coalesced
  unsigned short* xrow = xb + (size_t)t * D_DIM;
  #pragma unroll
  for (int j = 0; j < 8; ++j) {
    int idx = j * 16 + e;
    float4 v = *(const float4*)(xr + idx * 4);
    ushort4 o;
    o.x = f2bf(v.x); o.y = f2bf(v.y); o.z = f2bf(v.z); o.w = f2bf(v.w);
    ((ushort4*)xrow)[idx] = o;
  }

  float m = acc;
  for (int off = 8; off; off >>= 1) m = fmaxf(m, __shfl_xor(m, off));
  float p = expf(acc - m);
  float s = p;
  for (int off = 8; off; off >>= 1) s += __shfl_xor(s, off);
  float score = p / s;
  atomicAdd(&phil[e], score);

  float v1 = score; int i1 = e;
  for (int off = 8; off; off >>= 1) {
    float ov = __shfl_xor(v1, off); int oi = __shfl_xor(i1, off);
    if (ov > v1 || (ov == v1 && oi < i1)) { v1 = ov; i1 = oi; }
  }
  float sc2 = (e == i1) ? -1.f : score;
  float v2 = sc2; int i2 = e;
  for (int off = 8; off; off >>= 1) {
    float ov = __shfl_xor(v2, off); int oi = __shfl_xor(i2, off);
    if (ov > v2 || (ov == v2 && oi < i2)) { v2 = ov; i2 = oi; }
  }
  if (e == 0) {
    w_et[(size_t)i1 * T_TOK + t] = v1;
    w_et[(size_t)i2 * T_TOK + t] = v2;
  }
  __syncthreads();
  if (tid < E_EXP) atomicAdd(&phi_sum[tid], phil[tid]);
}

__global__ void aux_kernel(const float* __restrict__ phi_sum, float* __restrict__ out_aux) {
  if (threadIdx.x == 0) {
    float s = 0.f;
    for (int e = 0; e < E_EXP; ++e) {
      float pm = phi_sum[e] / (float)T_TOK;
      s += pm * pm;
    }
    *out_aux = (float)E_EXP * s;
  }
}

// ============ top-C selection: 3-level radix (11/11/10), wide grids ============
template<int P>
__global__ __launch_bounds__(256) void s_hist(
    const float* __restrict__ w_et, unsigned* __restrict__ hist,
    const unsigned* __restrict__ prefix, const unsigned* __restrict__ done) {
  int c = blockIdx.x, e = blockIdx.y, tid = threadIdx.x;
  if (P > 0 && done[e]) return;
  __shared__ unsigned lh[2048];
  for (int i = tid; i < 2048; i += 256) lh[i] = 0;
  __syncthreads();
  const float* w = w_et + (size_t)e * T_TOK + c * 2048;
  unsigned pfx = (P > 0) ? prefix[e] : 0u;
  #pragma unroll
  for (int i = 0; i < 8; ++i) {
    unsigned b = __float_as_uint(w[i * 256 + tid]);
    if (P == 0) { if (b) atomicAdd(&lh[b >> 21], 1u); }
    else if (P == 1) { if ((b >> 21) == (pfx >> 21)) atomicAdd(&lh[(b >> 10) & 0x7FFu], 1u); }
    else { if ((b >> 10) == (pfx >> 10)) atomicAdd(&lh[b & 0x3FFu], 1u); }
  }
  __syncthreads();
  for (int i = tid; i < 2048; i += 256)
    if (lh[i]) atomicAdd(&hist[e * 2048 + i], lh[i]);
}

template<int P>
__global__ __launch_bounds__(1024) void s_pick(
    const unsigned* __restrict__ hist, unsigned* __restrict__ prefix,
    unsigned* __restrict__ krem, unsigned* __restrict__ done) {
  int tid = threadIdx.x, lane = tid & 63, e = tid >> 6;
  if (P > 0 && done[e]) return;
  const int BPL = (P == 2) ? 16 : 32;
  const int SH = (P == 0) ? 21 : (P == 1) ? 10 : 0;
  const unsigned* h = hist + e * 2048;
  unsigned S = 0;
  for (int i = 0; i < BPL; ++i) S += h[lane * BPL + i];
  unsigned U = S;
  #pragma unroll
  for (int off = 1; off < 64; off <<= 1) {
    unsigned t = __shfl_down(U, off);
    if (lane + off < 64) U += t;
  }
  unsigned Unext = __shfl_down(U, 1);
  if (lane == 63) Unext = 0;
  unsigned k = (P == 0) ? (unsigned)C_CAP : krem[e];
  if (P == 0 && lane == 0) {
    if (U < k) { done[e] = 1; prefix[e] = 0; krem[e] = 0; }
    else done[e] = 0;
  }
  if (U >= k && Unext < k) {
    unsigned cum = Unext; int chosen = 0; unsigned knew = 0;
    for (int i = BPL - 1; i >= 0; --i) {
      unsigned hh = h[lane * BPL + i];
      if (cum + hh >= k) { chosen = lane * BPL + i; knew = k - cum; break; }
      cum += hh;
    }
    if (P == 0) prefix[e] = ((unsigned)chosen) << SH;
    else prefix[e] = prefix[e] | (((unsigned)chosen) << SH);
    krem[e] = knew;
  }
}

__global__ __launch_bounds__(256) void s_count(
    const float* __restrict__ w_et, const unsigned* __restrict__ prefix,
    unsigned* __restrict__ cnt) {
  int c = blockIdx.x, e = blockIdx.y, tid = threadIdx.x;
  unsigned thr = prefix[e];
  const uint4* up = (const uint4*)(w_et + (size_t)e * T_TOK + c * 2048 + tid * 8);
  uint4 va = up[0], vb = up[1];
  unsigned gt = 0, eq = 0;
  unsigned vals[8] = {va.x, va.y, va.z, va.w, vb.x, vb.y, vb.z, vb.w};
  #pragma unroll
  for (int i = 0; i < 8; ++i) {
    if (vals[i] > thr) gt++;
    else if (vals[i] == thr) eq++;
  }
  __shared__ unsigned sc[256];
  sc[tid] = (gt << 16) | eq;
  __syncthreads();
  for (int s = 128; s; s >>= 1) {
    if (tid < s) sc[tid] += sc[tid + s];
    __syncthreads();
  }
  if (tid == 0) cnt[e * 16 + c] = sc[0];
}

// s_write with fused per-expert base scan
__global__ __launch_bounds__(256) void s_write(
    const float* __restrict__ w_et, const unsigned* __restrict__ prefix,
    const unsigned* __restrict__ cnt,
    int* __restrict__ sel_idx, float* __restrict__ sel_w) {
  int c = blockIdx.x, e = blockIdx.y, tid = threadIdx.x;
  unsigned thr = prefix[e];
  __shared__ unsigned s_gb, s_eb, s_gt, s_eq;
  if (tid == 0) {
    unsigned g = 0, q = 0, gb = 0, eb = 0;
    #pragma unroll
    for (int c2 = 0; c2 < 16; ++c2) {
      unsigned p = cnt[e * 16 + c2];
      if (c2 < c) { gb += p >> 16; eb += p & 0xFFFFu; }
      g += p >> 16; q += p & 0xFFFFu;
    }
    s_gb = gb; s_eb = eb; s_gt = g; s_eq = (unsigned)C_CAP - g;
  }
  const uint4* up = (const uint4*)(w_et + (size_t)e * T_TOK + c * 2048 + tid * 8);
  uint4 va = up[0], vb = up[1];
  unsigned vals[8] = {va.x, va.y, va.z, va.w, vb.x, vb.y, vb.z, vb.w};
  unsigned gt = 0, eq = 0;
  #pragma unroll
  for (int i = 0; i < 8; ++i) {
    if (vals[i] > thr) gt++;
    else if (vals[i] == thr) eq++;
  }
  __shared__ unsigned sc[256];
  unsigned mine = (gt << 16) | eq;
  sc[tid] = mine;
  __syncthreads();
  for (int off = 1; off < 256; off <<= 1) {
    unsigned add = (tid >= off) ? sc[tid - off] : 0u;
    __syncthreads();
    sc[tid] += add;
    __syncthreads();
  }
  unsigned excl = sc[tid] - mine;
  unsigned gpos = s_gb + (excl >> 16);
  unsigned qpos = s_eb + (excl & 0xFFFFu);
  unsigned gtotal = s_gt, eqtake = s_eq;
  int* si = sel_idx + (size_t)e * C_CAP;
  float* sw = sel_w + (size_t)e * C_CAP;
  int tokbase = c * 2048 + tid * 8;
  #pragma unroll
  for (int i = 0; i < 8; ++i) {
    unsigned b = vals[i];
    if (b > thr) {
      si[gpos] = tokbase + i; sw[gpos] = __uint_as_float(b); gpos++;
    } else if (b == thr && qpos < eqtake) {
      si[gtotal + qpos] = tokbase + i; sw[gtotal + qpos] = __uint_as_float(b); qpos++;
    }
  }
}

// ===== GEMMs: BK=32, 3-buffer 2-deep pipeline, counted vmcnt =====
// LDS chunk swizzle (64B rows = 4x16B chunks): lds_chunk = k_chunk ^ ((row>>1)&3)
// gld16 dest linear; source pre-swizzled (rule #21).

#define PIPE_BARRIER() do { __builtin_amdgcn_s_barrier(); __builtin_amdgcn_sched_barrier(0); } while (0)

// ---- GEMM1: h = gather(x) @ w1[e], SwiGLU fused -> act bf16 ----
// grid e(16) x mt(16) x nt(16); tile 128 tok x (64 h1 + 64 h2); waves 2M x 2N
__global__ __launch_bounds__(256, 3) void gemm1_kernel(
    const unsigned short* __restrict__ xb,    // [T][D] bf16
    const unsigned short* __restrict__ w1t,   // [E][2F][D] bf16
    const int* __restrict__ sel_idx,          // [E][C]
    unsigned short* __restrict__ act) {       // [E][C][F] bf16
  __shared__ __align__(16) unsigned short As[3 * 4096];
  __shared__ __align__(16) unsigned short Bs[3 * 4096];
  int bid = (blockIdx.x & 7) * 512 + (blockIdx.x >> 3);
  int nt = bid & 15, mt = (bid >> 4) & 15, e = bid >> 8;
  int tid = threadIdx.x, lane = tid & 63, wid = tid >> 6;
  int wr = wid >> 1, wc = wid & 1;
  int cl = lane & 15, rg = lane >> 4;

  int c0 = tid, c1 = 256 + tid;
  int r0 = c0 >> 2, gk0 = (c0 & 3) ^ ((r0 >> 1) & 3);
  int r1 = c1 >> 2, gk1 = (c1 & 3) ^ ((r1 >> 1) & 3);
  int tok0 = sel_idx[e * C_CAP + mt * 128 + r0];
  int tok1 = sel_idx[e * C_CAP + mt * 128 + r1];
  const unsigned short* ag0 = xb + (size_t)tok0 * D_DIM + gk0 * 8;
  const unsigned short* ag1 = xb + (size_t)tok1 * D_DIM + gk1 * 8;
  int hcol0 = (r0 < 64) ? (nt * 64 + r0) : (F_DIM + nt * 64 + (r0 - 64));
  int hcol1 = (r1 < 64) ? (nt * 64 + r1) : (F_DIM + nt * 64 + (r1 - 64));
  const unsigned short* bg0 = w1t + ((size_t)e * 2 * F_DIM + hcol0) * D_DIM + gk0 * 8;
  const unsigned short* bg1 = w1t + ((size_t)e * 2 * F_DIM + hcol1) * D_DIM + gk1 * 8;
  char* Ab = (char*)As;
  char* Bb = (char*)Bs;

#define G1_STAGE(buf, kt) do { \
    gld16(ag0 + (kt) * 32, Ab + (buf) * 8192 + tid * 16); \
    gld16(ag1 + (kt) * 32, Ab + (buf) * 8192 + 4096 + tid * 16); \
    gld16(bg0 + (kt) * 32, Bb + (buf) * 8192 + tid * 16); \
    gld16(bg1 + (kt) * 32, Bb + (buf) * 8192 + 4096 + tid * 16); \
  } while (0)

  f32x4 zero = {0.f, 0.f, 0.f, 0.f};
  f32x4 acc[4][4];
  #pragma unroll
  for (int m = 0; m < 4; ++m)
    #pragma unroll
    for (int n = 0; n < 4; ++n) acc[m][n] = zero;

#define G1_COMPUTE(buf) do { \
    const unsigned short* Ap = As + (buf) * 4096; \
    const unsigned short* Bp = Bs + (buf) * 4096; \
    bf16x8 av[4], bv[4]; \
    _Pragma("unroll") \
    for (int m = 0; m < 4; ++m) { \
      int ra = wr * 64 + m * 16 + cl; \
      av[m] = *(const bf16x8*)&Ap[(ra * 4 + (rg ^ ((ra >> 1) & 3))) * 8]; \
    } \
    _Pragma("unroll") \
    for (int n = 0; n < 4; ++n) { \
      int rb = ((n < 2) ? (wc * 32 + n * 16) : (64 + wc * 32 + (n - 2) * 16)) + cl; \
      bv[n] = *(const bf16x8*)&Bp[(rb * 4 + (rg ^ ((rb >> 1) & 3))) * 8]; \
    } \
    _Pragma("unroll") \
    for (int m = 0; m < 4; ++m) \
      _Pragma("unroll") \
      for (int n = 0; n < 4; ++n) \
        acc[m][n] = __builtin_amdgcn_mfma_f32_16x16x32_bf16(av[m], bv[n], acc[m][n], 0, 0, 0); \
  } while (0)

  const int NK = D_DIM / 32;  // 16
  G1_STAGE(0, 0);
  G1_STAGE(1, 1);
  int bc = 0, bs = 2;
  for (int kt = 0; kt < NK - 1; ++kt) {
    asm volatile("s_waitcnt vmcnt(4)" ::: "memory");
    PIPE_BARRIER();
    if (kt + 2 < NK) { G1_STAGE(bs, kt + 2); bs = (bs == 2) ? 0 : bs + 1; }
    __builtin_amdgcn_sched_barrier(0);
    G1_COMPUTE(bc);
    bc = (bc == 2) ? 0 : bc + 1;
  }
  asm volatile("s_waitcnt vmcnt(0)" ::: "memory");
  PIPE_BARRIER();
  G1_COMPUTE(bc);

  // SwiGLU epilogue: n in {0,1} = h1 frags, n+2 = matching h2 frags
  #pragma unroll
  for (int m = 0; m < 4; ++m) {
    #pragma unroll
    for (int n = 0; n < 2; ++n) {
      #pragma unroll
      for (int r = 0; r < 4; ++r) {
        int row = mt * 128 + wr * 64 + m * 16 + rg * 4 + r;
        int col = nt * 64 + wc * 32 + n * 16 + cl;
        float h1 = acc[m][n][r];
        float h2 = acc[m][n + 2][r];
        float sg = h2 / (1.f + __expf(-h2));
        act[((size_t)e * C_CAP + row) * F_DIM + col] = f2bf(h1 * sg);
      }
    }
  }
#undef G1_STAGE
#undef G1_COMPUTE
}

// ---- GEMM2: out = act @ w2[e] * sel_w, scatter-add ----
__global__ __launch_bounds__(256, 3) void gemm2_kernel(
    const unsigned short* __restrict__ act,   // [E][C][F] bf16
    const unsigned short* __restrict__ w2t,   // [E][D][F] bf16
    const int* __restrict__ sel_idx,
    const float* __restrict__ sel_w,
    float* __restrict__ out) {                // [T][D] fp32
  __shared__ __align__(16) unsigned short As[3 * 4096];
  __shared__ __align__(16) unsigned short Bs[3 * 4096];
  int bid = (blockIdx.x & 7) * 128 + (blockIdx.x >> 3);
  int nt = bid & 3, mt = (bid >> 2) & 15, e = bid >> 6;
  int tid = threadIdx.x, lane = tid & 63, wid = tid >> 6;
  int wr = wid >> 1, wc = wid & 1;
  int cl = lane & 15, rg = lane >> 4;

  int c0 = tid, c1 = 256 + tid;
  int r0 = c0 >> 2, gk0 = (c0 & 3) ^ ((r0 >> 1) & 3);
  int r1 = c1 >> 2, gk1 = (c1 & 3) ^ ((r1 >> 1) & 3);
  const unsigned short* ag0 = act + ((size_t)e * C_CAP + mt * 128 + r0) * F_DIM + gk0 * 8;
  const unsigned short* ag1 = act + ((size_t)e * C_CAP + mt * 128 + r1) * F_DIM + gk1 * 8;
  const unsigned short* bg0 = w2t + ((size_t)e * D_DIM + nt * 128 + r0) * F_DIM + gk0 * 8;
  const unsigned short* bg1 = w2t + ((size_t)e * D_DIM + nt * 128 + r1) * F_DIM + gk1 * 8;
  char* Ab = (char*)As;
  char* Bb = (char*)Bs;

#define G2_STAGE(buf, kt) do { \
    gld16(ag0 + (kt) * 32, Ab + (buf) * 8192 + tid * 16); \
    gld16(ag1 + (kt) * 32, Ab + (buf) * 8192 + 4096 + tid * 16); \
    gld16(bg0 + (kt) * 32, Bb + (buf) * 8192 + tid * 16); \
    gld16(bg1 + (kt) * 32, Bb + (buf) * 8192 + 4096 + tid * 16); \
  } while (0)

  f32x4 zero = {0.f, 0.f, 0.f, 0.f};
  f32x4 acc[4][4];
  #pragma unroll
  for (int m = 0; m < 4; ++m)
    #pragma unroll
    for (int n = 0; n < 4; ++n) acc[m][n] = zero;

#define G2_COMPUTE(buf) do { \
    const unsigned short* Ap = As + (buf) * 4096; \
    const unsigned short* Bp = Bs + (buf) * 4096; \
    bf16x8 av[4], bv[4]; \
    _Pragma("unroll") \
    for (int m = 0; m < 4; ++m) { \
      int ra = wr * 64 + m * 16 + cl; \
      av[m] = *(const bf16x8*)&Ap[(ra * 4 + (rg ^ ((ra >> 1) & 3))) * 8]; \
    } \
    _Pragma("unroll") \
    for (int n = 0; n < 4; ++n) { \
      int rb = wc * 64 + n * 16 + cl; \
      bv[n] = *(const bf16x8*)&Bp[(rb * 4 + (rg ^ ((rb >> 1) & 3))) * 8]; \
    } \
    _Pragma("unroll") \
    for (int m = 0; m < 4; ++m) \
      _Pragma("unroll") \
      for (int n = 0; n < 4; ++n) \
        acc[m][n] = __builtin_amdgcn_mfma_f32_16x16x32_bf16(av[m], bv[n], acc[m][n], 0, 0, 0); \
  } while (0)

  const int NK = F_DIM / 32;  // 32
  G2_STAGE(0, 0);
  G2_STAGE(1, 1);
  int bc = 0, bs = 2;
  for (int kt = 0; kt < NK - 1; ++kt) {
    asm volatile("s_waitcnt vmcnt(4)" ::: "memory");
    PIPE_BARRIER();
    if (kt + 2 < NK) { G2_STAGE(bs, kt + 2); bs = (bs == 2) ? 0 : bs + 1; }
    __builtin_amdgcn_sched_barrier(0);
    G2_COMPUTE(bc);
    bc = (bc == 2) ? 0 : bc + 1;
  }
  asm volatile("s_waitcnt vmcnt(0)" ::: "memory");
  PIPE_BARRIER();
  G2_COMPUTE(bc);

  #pragma unroll
  for (int m = 0; m < 4; ++m) {
    #pragma unroll
    for (int r = 0; r < 4; ++r) {
      int slot = mt * 128 + wr * 64 + m * 16 + rg * 4 + r;
      float wgt = sel_w[e * C_CAP + slot];
      int tok = sel_idx[e * C_CAP + slot];
      float* orow = out + (size_t)tok * D_DIM;
      #pragma unroll
      for (int n = 0; n < 4; ++n) {
        int col = nt * 128 + wc * 64 + n * 16 + cl;
        atomicAdd(&orow[col], acc[m][n][r] * wgt);
      }
    }
  }
#undef G2_STAGE
#undef G2_COMPUTE
}

// ---------------- launch ----------------
extern "C" void kernel_launch(void* const* d_in, const int* in_sizes, int n_in,
                              void* d_out, int out_size, void* d_ws, size_t ws_size,
                              hipStream_t stream) {
  const float* x  = (const float*)d_in[0];
  const float* wg = (const float*)d_in[1];
  const float* w1 = (const float*)d_in[2];
  const float* w2 = (const float*)d_in[3];
  float* out = (float*)d_out;

  char* ws = (char*)d_ws;
  size_t off = 0;
  auto carve = [&](size_t bytes) -> void* {
    void* p = ws + off;
    off += (bytes + 255) & ~(size_t)255;
    return p;
  };
  float* w_et            = (float*)carve((size_t)E_EXP * T_TOK * 4);
  float* phi             = (float*)carve(64);
  int* sel_i             = (int*)carve((size_t)E_EXP * C_CAP * 4);
  float* sel_wv          = (float*)carve((size_t)E_EXP * C_CAP * 4);
  unsigned short* xb     = (unsigned short*)carve((size_t)T_TOK * D_DIM * 2);
  unsigned short* w1t    = (unsigned short*)carve((size_t)E_EXP * 2 * F_DIM * D_DIM * 2);
  unsigned short* w2t    = (unsigned short*)carve((size_t)E_EXP * D_DIM * F_DIM * 2);
  unsigned short* actb   = (unsigned short*)carve((size_t)E_EXP * C_CAP * F_DIM * 2);
  unsigned* hist0        = (unsigned*)carve((size_t)E_EXP * 2048 * 4);
  unsigned* hist1        = (unsigned*)carve((size_t)E_EXP * 2048 * 4);
  unsigned* hist2        = (unsigned*)carve((size_t)E_EXP * 2048 * 4);
  unsigned* prefix       = (unsigned*)carve(64 * 4);
  unsigned* krem         = (unsigned*)carve(64 * 4);
  unsigned* done         = (unsigned*)carve(64 * 4);
  unsigned* cnt          = (unsigned*)carve(256 * 4);
  if (off > ws_size) return;

  hipMemsetAsync(w_et, 0, (size_t)E_EXP * T_TOK * 4, stream);
  hipMemsetAsync(phi, 0, 64, stream);
  hipMemsetAsync(hist0, 0, (size_t)E_EXP * 2048 * 4 * 3, stream);  // hist0..2 contiguous
  hipMemsetAsync(d_out, 0, (size_t)out_size * 4, stream);

  transpose_conv_kernel<<<dim3(2 * F_DIM / 32, D_DIM / 32, E_EXP), dim3(32, 8), 0, stream>>>(
      w1, w1t, D_DIM, 2 * F_DIM);
  transpose_conv_kernel<<<dim3(D_DIM / 32, F_DIM / 32, E_EXP), dim3(32, 8), 0, stream>>>(
      w2, w2t, F_DIM, D_DIM);
  gate_kernel<<<T_TOK / 16, 256, 0, stream>>>(x, wg, w_et, phi, xb);

  s_hist<0><<<dim3(16, 16), 256, 0, stream>>>(w_et, hist0, prefix, done);
  s_pick<0><<<1, 1024, 0, stream>>>(hist0, prefix, krem, done);
  s_hist<1><<<dim3(16, 16), 256, 0, stream>>>(w_et, hist1, prefix, done);
  s_pick<1><<<1, 1024, 0, stream>>>(hist1, prefix, krem, done);
  s_hist<2><<<dim3(16, 16), 256, 0, stream>>>(w_et, hist2, prefix, done);
  s_pick<2><<<1, 1024, 0, stream>>>(hist2, prefix, krem, done);
  s_count<<<dim3(16, 16), 256, 0, stream>>>(w_et, prefix, cnt);
  s_write<<<dim3(16, 16), 256, 0, stream>>>(w_et, prefix, cnt, sel_i, sel_wv);

  aux_kernel<<<1, 64, 0, stream>>>(phi, out + (size_t)T_TOK * D_DIM);
  gemm1_kernel<<<E_EXP * 16 * 16, 256, 0, stream>>>(xb, w1t, sel_i, actb);
  gemm2_kernel<<<E_EXP * 16 * 4, 256, 0, stream>>>(actb, w2t, sel_i, sel_wv, out);
}